// Round 5
// baseline (179.571 us; speedup 1.0000x reference)
//
#include <hip/hip_runtime.h>
#include <math.h>

#define N_ATOMS 100000
#define N_EDGES 6400000
#define NZB 50000          // ceil(N_ATOMS/2) z-nibble bytes
#define TBL_BYTES (N_ATOMS * 16)           // float4 P table
#define XY_OFF    TBL_BYTES                // 1,600,000 (16B aligned)
#define Z_OFF     (XY_OFF + N_ATOMS)       // 1,700,000 (16B aligned)
#define WS_NEED   (Z_OFF + NZB)

// cell(x): width-6 cells over [-48,48], clamped. Cell gap >= 2 in any dim
// guarantees |delta| >= 6 -> dr >= 6 -> cos_cutoff == 0 exactly in fp32 ->
// zero contribution. Conservative reject; survivors ~10%.
__device__ __forceinline__ int cell6(float x) {
    return min(max((int)((x + 48.0f) * (1.0f / 6.0f)), 0), 15);
}

__global__ __launch_bounds__(256)
void build_tables(const float* __restrict__ R, const int* __restrict__ Z,
                  float4* __restrict__ P, unsigned char* __restrict__ gxy,
                  unsigned char* __restrict__ gz) {
    int i = blockIdx.x * blockDim.x + threadIdx.x;
    if (i < N_ATOMS) {
        float x = R[3 * i], y = R[3 * i + 1], z = R[3 * i + 2];
        P[i] = make_float4(x, y, z, (float)Z[i]);
        gxy[i] = (unsigned char)(cell6(x) | (cell6(y) << 4));
    }
    if (i < NZB) {  // one thread per packed z-byte (2 atoms) -> no write race
        int a0 = 2 * i, a1 = 2 * i + 1;
        int c0 = cell6(R[3 * a0 + 2]);
        int c1 = (a1 < N_ATOMS) ? cell6(R[3 * a1 + 2]) : 0;
        gz[i] = (unsigned char)(c0 | (c1 << 4));
    }
}

// R5: fully branch-free main loop. R4's wall was 4 serialized `if(pass[u])`
// bodies per iteration, each with a dependent gather chain (~400cyc) + powz
// LDS read (~120cyc) + exec save/restore + vmcnt drain. Now: one basic block
// per iteration; gathers predicated via P[pass?a:0] (non-pass lanes share one
// cacheline -> TA coalesces; fills stay ~= survivors); physics computed for
// all lanes (bounded garbage, no NaN) and zeroed by select; powz LUT replaced
// with inline __powf (same values -- LUT was built with __powf).
__global__ __launch_bounds__(1024, 4)
void zbl_bfree(const float4* __restrict__ P,
               const unsigned char* __restrict__ gxy,
               const unsigned char* __restrict__ gz,
               const int*    __restrict__ idx,
               const float*  __restrict__ a_exp,
               const float*  __restrict__ a_num,
               const float*  __restrict__ coef,
               const float*  __restrict__ expo,
               float*        __restrict__ out)
{
    __shared__ __align__(16) unsigned char sxy[N_ATOMS];  // 100 KB
    __shared__ __align__(16) unsigned char sz[NZB];       // 50 KB
    __shared__ float wave_part[16];

    const int t = threadIdx.x;

    // cooperative LDS table load (uint4-vectorized; sizes divide 16 exactly)
    {
        const uint4* s = (const uint4*)gxy;
        uint4*       d = (uint4*)sxy;
        for (int k = t; k < N_ATOMS / 16; k += 1024) d[k] = s[k];
        const uint4* s2 = (const uint4*)gz;
        uint4*       d2 = (uint4*)sz;
        for (int k = t; k < NZB / 16; k += 1024) d2[k] = s2[k];
    }

    const float aexp     = a_exp[0];
    const float inv_anum = 1.0f / a_num[0];
    const float c0 = coef[0], c1 = coef[1], c2 = coef[2], c3 = coef[3];
    const float e0 = expo[0], e1 = expo[1], e2 = expo[2], e3 = expo[3];
    __syncthreads();

    const int4* idx_i4 = (const int4*)idx;              // idx[0,:]
    const int4* idx_j4 = (const int4*)(idx + N_EDGES);  // idx[1,:]
    const int n4 = N_EDGES / 4;                          // 1.6M exact
    const int tid    = blockIdx.x * blockDim.x + t;
    const int stride = gridDim.x * blockDim.x;

    const float PI_OVER_RMAX = 0.52359877559829887f;  // pi/6

    float acc = 0.0f;
    for (int k = tid; k < n4; k += stride) {
        int4 ii = idx_i4[k];
        int4 jj = idx_j4[k];

        // ---- stage 1: indices + batched LDS cell tests (branch-free) ----
        unsigned ia[4], jb[4];
        int cxa[4], cxb[4], cza[4], czb[4];
        bool valid[4];
#pragma unroll
        for (int u = 0; u < 4; ++u) {
            int i = (&ii.x)[u];
            int j = (&jj.x)[u];
            valid[u] = ((unsigned)i < N_ATOMS) & ((unsigned)j < N_ATOMS);
            unsigned a = min((unsigned)i, N_ATOMS - 1u);
            unsigned b = min((unsigned)j, N_ATOMS - 1u);
            ia[u] = a; jb[u] = b;
            cxa[u] = sxy[a];                          // LDS byte reads batch
            cxb[u] = sxy[b];
            cza[u] = (sz[a >> 1] >> ((a & 1) << 2)) & 15;
            czb[u] = (sz[b >> 1] >> ((b & 1) << 2)) & 15;
        }
        bool pass[4];
#pragma unroll
        for (int u = 0; u < 4; ++u) {
            int dxy = abs((cxa[u] & 15) - (cxb[u] & 15))
                    | abs((cxa[u] >> 4) - (cxb[u] >> 4))
                    | abs(cza[u] - czb[u]);
            pass[u] = valid[u] & (dxy <= 1);
        }

        // ---- stage 2a: 8 predicated gathers, all in flight ----
        // non-pass lanes read P[0] (one shared cacheline, TA-coalesced)
        float4 pa[4], pb[4];
#pragma unroll
        for (int u = 0; u < 4; ++u) {
            pa[u] = P[pass[u] ? ia[u] : 0u];
            pb[u] = P[pass[u] ? jb[u] : 0u];
        }

        // ---- stage 2b: branch-free physics, zeroed by select ----
#pragma unroll
        for (int u = 0; u < 4; ++u) {
            float dx = pb[u].x - pa[u].x;
            float dy = pb[u].y - pa[u].y;
            float dz = pb[u].z - pa[u].z;
            float d2 = dx * dx + dy * dy + dz * dz;
            bool live = pass[u] & (d2 < 36.0f);
            float dr = fmaxf(sqrtf(d2), 0.02f);           // [0.02, 6) when live
            float zi = pa[u].w, zj = pb[u].w;              // >= 1 always
            float dist = dr * (__powf(zi, aexp) + __powf(zj, aexp)) * inv_anum;
            float f = c0 * __expf(-e0 * dist) + c1 * __expf(-e1 * dist)
                    + c2 * __expf(-e2 * dist) + c3 * __expf(-e3 * dist);
            float cc = 0.5f * (__cosf(PI_OVER_RMAX * dr) + 1.0f);
            float term = 0.5f * zi * zj / dr * f * cc;
            acc += live ? term : 0.0f;
        }
    }

    // wave (64-lane) shuffle reduction, then 16-wave LDS reduction
#pragma unroll
    for (int off = 32; off > 0; off >>= 1)
        acc += __shfl_down(acc, off, 64);
    const int lane = t & 63;
    const int wave = t >> 6;
    if (lane == 0) wave_part[wave] = acc;
    __syncthreads();
    if (t == 0) {
        float s = 0.0f;
#pragma unroll
        for (int w = 0; w < 16; ++w) s += wave_part[w];
        atomicAdd(out, s);
    }
}

// Fallback (ws too small for tables): packed-gather MLP version (R3).
__global__ __launch_bounds__(256)
void zbl_mlp(const float4* __restrict__ P, const int* __restrict__ idx,
             const float* __restrict__ a_exp, const float* __restrict__ a_num,
             const float* __restrict__ coef, const float* __restrict__ expo,
             float* __restrict__ out)
{
    __shared__ float wave_part[4];
    const float aexp = a_exp[0];
    const float inv_anum = 1.0f / a_num[0];
    const float c0 = coef[0], c1 = coef[1], c2 = coef[2], c3 = coef[3];
    const float e0 = expo[0], e1 = expo[1], e2 = expo[2], e3 = expo[3];
    const int t = threadIdx.x;
    const int4* idx_i4 = (const int4*)idx;
    const int4* idx_j4 = (const int4*)(idx + N_EDGES);
    const int n4 = N_EDGES / 4;
    const int tid = blockIdx.x * blockDim.x + t;
    const int stride = gridDim.x * blockDim.x;
    const float PI_OVER_RMAX = 0.52359877559829887f;
    float acc = 0.0f;
    for (int k = tid; k < n4; k += stride) {
        int4 ii = idx_i4[k];
        int4 jj = idx_j4[k];
        float4 pa[4], pb[4];
        bool valid[4];
#pragma unroll
        for (int u = 0; u < 4; ++u) {
            int i = (&ii.x)[u], j = (&jj.x)[u];
            valid[u] = ((unsigned)i < N_ATOMS) & ((unsigned)j < N_ATOMS);
            pa[u] = P[min((unsigned)i, N_ATOMS - 1u)];
            pb[u] = P[min((unsigned)j, N_ATOMS - 1u)];
        }
#pragma unroll
        for (int u = 0; u < 4; ++u) {
            float dx = pb[u].x - pa[u].x, dy = pb[u].y - pa[u].y, dz = pb[u].z - pa[u].z;
            float d2 = dx * dx + dy * dy + dz * dz;
            if (valid[u] && d2 < 36.0f) {
                float dr = fmaxf(sqrtf(d2), 0.02f);
                float zi = pa[u].w, zj = pb[u].w;
                float dist = dr * (__powf(zi, aexp) + __powf(zj, aexp)) * inv_anum;
                float f = c0 * __expf(-e0 * dist) + c1 * __expf(-e1 * dist)
                        + c2 * __expf(-e2 * dist) + c3 * __expf(-e3 * dist);
                float cc = 0.5f * (__cosf(PI_OVER_RMAX * dr) + 1.0f);
                acc += 0.5f * zi * zj / dr * f * cc;
            }
        }
    }
#pragma unroll
    for (int off = 32; off > 0; off >>= 1)
        acc += __shfl_down(acc, off, 64);
    const int lane = t & 63, wave = t >> 6;
    if (lane == 0) wave_part[wave] = acc;
    __syncthreads();
    if (t == 0)
        atomicAdd(out, wave_part[0] + wave_part[1] + wave_part[2] + wave_part[3]);
}

extern "C" void kernel_launch(void* const* d_in, const int* in_sizes, int n_in,
                              void* d_out, int out_size, void* d_ws, size_t ws_size,
                              hipStream_t stream) {
    const float* R     = (const float*)d_in[0];
    const int*   Z     = (const int*)d_in[1];
    const int*   idx   = (const int*)d_in[2];
    const float* a_exp = (const float*)d_in[3];
    const float* a_num = (const float*)d_in[4];
    const float* coef  = (const float*)d_in[5];
    const float* expo  = (const float*)d_in[6];
    float* out = (float*)d_out;

    hipMemsetAsync(out, 0, sizeof(float), stream);  // d_out poisoned each call

    if (ws_size >= (size_t)WS_NEED) {
        float4*        P   = (float4*)d_ws;
        unsigned char* gxy = (unsigned char*)d_ws + XY_OFF;
        unsigned char* gz  = (unsigned char*)d_ws + Z_OFF;
        build_tables<<<(N_ATOMS + 255) / 256, 256, 0, stream>>>(R, Z, P, gxy, gz);
        // 150 KB LDS -> 1 block/CU; VGPR capped at 128 so 16 waves/CU hold
        zbl_bfree<<<256, 1024, 0, stream>>>(P, gxy, gz, idx,
                                            a_exp, a_num, coef, expo, out);
    } else if (ws_size >= (size_t)TBL_BYTES) {
        float4* P = (float4*)d_ws;
        build_tables<<<(N_ATOMS + 255) / 256, 256, 0, stream>>>(
            R, Z, P, (unsigned char*)d_ws, (unsigned char*)d_ws);  // tails unused
        zbl_mlp<<<2048, 256, 0, stream>>>(P, idx, a_exp, a_num, coef, expo, out);
    }
}

// Round 6
// 166.434 us; speedup vs baseline: 1.0789x; 1.0789x over previous
//
#include <hip/hip_runtime.h>
#include <math.h>

#define N_ATOMS 100000
#define N_EDGES 6400000
#define NZB 50000          // ceil(N_ATOMS/2) z-nibble bytes
#define TBL_BYTES (N_ATOMS * 16)           // float4 P table
#define XY_OFF    TBL_BYTES                // 1,600,000 (16B aligned)
#define Z_OFF     (XY_OFF + N_ATOMS)       // 1,700,000 (16B aligned)
#define WS_NEED   (Z_OFF + NZB)

// cell(x): width-6 cells over [-48,48], clamped. Cell gap >= 2 in any dim
// guarantees |delta| >= 6 -> dr >= 6 -> cos_cutoff == 0 exactly in fp32 ->
// zero contribution. Conservative reject; ~10.5% of edges survive.
__device__ __forceinline__ int cell6(float x) {
    return min(max((int)((x + 48.0f) * (1.0f / 6.0f)), 0), 15);
}

__global__ __launch_bounds__(256)
void build_tables(const float* __restrict__ R, const int* __restrict__ Z,
                  float4* __restrict__ P, unsigned char* __restrict__ gxy,
                  unsigned char* __restrict__ gz) {
    int i = blockIdx.x * blockDim.x + threadIdx.x;
    if (i < N_ATOMS) {
        float x = R[3 * i], y = R[3 * i + 1], z = R[3 * i + 2];
        P[i] = make_float4(x, y, z, (float)Z[i]);
        gxy[i] = (unsigned char)(cell6(x) | (cell6(y) << 4));
    }
    if (i < NZB) {  // one thread per packed z-byte (2 atoms) -> no write race
        int a0 = 2 * i, a1 = 2 * i + 1;
        int c0 = cell6(R[3 * a0 + 2]);
        int c1 = (a1 < N_ATOMS) ? cell6(R[3 * a1 + 2]) : 0;
        gz[i] = (unsigned char)(c0 | (c1 << 4));
    }
}

// R6 = R4 structure + fixes:
//  - gathers predicated & hoisted BEFORE physics (8 dwordx4 in flight;
//    non-pass lanes index P[0] -> one broadcast cacheline). Kills R4's four
//    serialized per-body gather chains.
//  - physics exec-masked (R5's dense-transcendental mistake reverted); body
//    is pure VALU, no memory ops -> no vmcnt/lgkm drain inside.
//  - z-nibble LDS reads predicated on xy pass (masked lanes -> addr 0
//    broadcast) to cut random-bank conflict pressure.
//  - plain __launch_bounds__(1024): R5's (1024,4) made the compiler chase
//    8 waves/EU (impossible under 150KB LDS), cap VGPR=64, and spill 10MB
//    of scratch per dispatch. R4 proved 52 VGPR / no spill with the plain
//    bound.
__global__ __launch_bounds__(1024)
void zbl_sparse(const float4* __restrict__ P,
                const unsigned char* __restrict__ gxy,
                const unsigned char* __restrict__ gz,
                const int*    __restrict__ idx,
                const float*  __restrict__ a_exp,
                const float*  __restrict__ a_num,
                const float*  __restrict__ coef,
                const float*  __restrict__ expo,
                float*        __restrict__ out)
{
    __shared__ __align__(16) unsigned char sxy[N_ATOMS];  // 100 KB
    __shared__ __align__(16) unsigned char sz[NZB];       // 50 KB
    __shared__ float wave_part[16];

    const int t = threadIdx.x;

    // cooperative LDS table load (uint4-vectorized; sizes divide 16 exactly)
    {
        const uint4* s = (const uint4*)gxy;
        uint4*       d = (uint4*)sxy;
        for (int k = t; k < N_ATOMS / 16; k += 1024) d[k] = s[k];
        const uint4* s2 = (const uint4*)gz;
        uint4*       d2 = (uint4*)sz;
        for (int k = t; k < NZB / 16; k += 1024) d2[k] = s2[k];
    }

    const float aexp     = a_exp[0];
    const float inv_anum = 1.0f / a_num[0];
    const float c0 = coef[0], c1 = coef[1], c2 = coef[2], c3 = coef[3];
    const float e0 = expo[0], e1 = expo[1], e2 = expo[2], e3 = expo[3];
    __syncthreads();

    const int4* idx_i4 = (const int4*)idx;              // idx[0,:]
    const int4* idx_j4 = (const int4*)(idx + N_EDGES);  // idx[1,:]
    const int n4 = N_EDGES / 4;                          // 1.6M exact
    const int tid    = blockIdx.x * blockDim.x + t;
    const int stride = gridDim.x * blockDim.x;

    const float PI_OVER_RMAX = 0.52359877559829887f;  // pi/6

    float acc = 0.0f;
    for (int k = tid; k < n4; k += stride) {
        int4 ii = idx_i4[k];
        int4 jj = idx_j4[k];

        // ---- stage 1a: indices + xy cell test (8 random LDS byte reads) ----
        unsigned ia[4], jb[4];
        bool pxy[4];
#pragma unroll
        for (int u = 0; u < 4; ++u) {
            int i = (&ii.x)[u];
            int j = (&jj.x)[u];
            bool valid = ((unsigned)i < N_ATOMS) & ((unsigned)j < N_ATOMS);
            unsigned a = min((unsigned)i, N_ATOMS - 1u);
            unsigned b = min((unsigned)j, N_ATOMS - 1u);
            ia[u] = a; jb[u] = b;
            int ci = sxy[a], cj = sxy[b];
            int dxy = abs((ci & 15) - (cj & 15)) | abs((ci >> 4) - (cj >> 4));
            pxy[u] = valid & (dxy <= 1);
        }

        // ---- stage 1b: z test, LDS reads predicated on xy pass ----
        // (~78% of lanes read sz[0] -> same-address broadcast, no conflicts)
        bool pass[4];
#pragma unroll
        for (int u = 0; u < 4; ++u) {
            unsigned a = ia[u], b = jb[u];
            unsigned aa = pxy[u] ? (a >> 1) : 0u;
            unsigned ba = pxy[u] ? (b >> 1) : 0u;
            int za = (sz[aa] >> ((a & 1) << 2)) & 15;
            int zb = (sz[ba] >> ((b & 1) << 2)) & 15;
            pass[u] = pxy[u] & (abs(za - zb) <= 1);
        }

        // ---- stage 2a: 8 predicated gathers, all in flight (MLP=8) ----
        float4 pa[4], pb[4];
#pragma unroll
        for (int u = 0; u < 4; ++u) {
            pa[u] = P[pass[u] ? ia[u] : 0u];
            pb[u] = P[pass[u] ? jb[u] : 0u];
        }

        // ---- stage 2b: exec-masked physics, pure VALU inside ----
#pragma unroll
        for (int u = 0; u < 4; ++u) {
            float dx = pb[u].x - pa[u].x;
            float dy = pb[u].y - pa[u].y;
            float dz = pb[u].z - pa[u].z;
            float d2 = dx * dx + dy * dy + dz * dz;
            bool live = pass[u] & (d2 < 36.0f);   // pass guards P[0] dummies
            if (live) {
                float dr = fmaxf(sqrtf(d2), 0.02f);  // clip [0.02, 6)
                float zi = pa[u].w, zj = pb[u].w;     // >= 1
                float dist = dr * (__powf(zi, aexp) + __powf(zj, aexp)) * inv_anum;
                float f = c0 * __expf(-e0 * dist) + c1 * __expf(-e1 * dist)
                        + c2 * __expf(-e2 * dist) + c3 * __expf(-e3 * dist);
                float cc = 0.5f * (__cosf(PI_OVER_RMAX * dr) + 1.0f);
                acc += 0.5f * zi * zj / dr * f * cc;
            }
        }
    }

    // wave (64-lane) shuffle reduction, then 16-wave LDS reduction
#pragma unroll
    for (int off = 32; off > 0; off >>= 1)
        acc += __shfl_down(acc, off, 64);
    const int lane = t & 63;
    const int wave = t >> 6;
    if (lane == 0) wave_part[wave] = acc;
    __syncthreads();
    if (t == 0) {
        float s = 0.0f;
#pragma unroll
        for (int w = 0; w < 16; ++w) s += wave_part[w];
        atomicAdd(out, s);
    }
}

// Fallback (ws too small for tables): packed-gather MLP version (R3).
__global__ __launch_bounds__(256)
void zbl_mlp(const float4* __restrict__ P, const int* __restrict__ idx,
             const float* __restrict__ a_exp, const float* __restrict__ a_num,
             const float* __restrict__ coef, const float* __restrict__ expo,
             float* __restrict__ out)
{
    __shared__ float wave_part[4];
    const float aexp = a_exp[0];
    const float inv_anum = 1.0f / a_num[0];
    const float c0 = coef[0], c1 = coef[1], c2 = coef[2], c3 = coef[3];
    const float e0 = expo[0], e1 = expo[1], e2 = expo[2], e3 = expo[3];
    const int t = threadIdx.x;
    const int4* idx_i4 = (const int4*)idx;
    const int4* idx_j4 = (const int4*)(idx + N_EDGES);
    const int n4 = N_EDGES / 4;
    const int tid = blockIdx.x * blockDim.x + t;
    const int stride = gridDim.x * blockDim.x;
    const float PI_OVER_RMAX = 0.52359877559829887f;
    float acc = 0.0f;
    for (int k = tid; k < n4; k += stride) {
        int4 ii = idx_i4[k];
        int4 jj = idx_j4[k];
        float4 pa[4], pb[4];
        bool valid[4];
#pragma unroll
        for (int u = 0; u < 4; ++u) {
            int i = (&ii.x)[u], j = (&jj.x)[u];
            valid[u] = ((unsigned)i < N_ATOMS) & ((unsigned)j < N_ATOMS);
            pa[u] = P[min((unsigned)i, N_ATOMS - 1u)];
            pb[u] = P[min((unsigned)j, N_ATOMS - 1u)];
        }
#pragma unroll
        for (int u = 0; u < 4; ++u) {
            float dx = pb[u].x - pa[u].x, dy = pb[u].y - pa[u].y, dz = pb[u].z - pa[u].z;
            float d2 = dx * dx + dy * dy + dz * dz;
            if (valid[u] && d2 < 36.0f) {
                float dr = fmaxf(sqrtf(d2), 0.02f);
                float zi = pa[u].w, zj = pb[u].w;
                float dist = dr * (__powf(zi, aexp) + __powf(zj, aexp)) * inv_anum;
                float f = c0 * __expf(-e0 * dist) + c1 * __expf(-e1 * dist)
                        + c2 * __expf(-e2 * dist) + c3 * __expf(-e3 * dist);
                float cc = 0.5f * (__cosf(PI_OVER_RMAX * dr) + 1.0f);
                acc += 0.5f * zi * zj / dr * f * cc;
            }
        }
    }
#pragma unroll
    for (int off = 32; off > 0; off >>= 1)
        acc += __shfl_down(acc, off, 64);
    const int lane = t & 63, wave = t >> 6;
    if (lane == 0) wave_part[wave] = acc;
    __syncthreads();
    if (t == 0)
        atomicAdd(out, wave_part[0] + wave_part[1] + wave_part[2] + wave_part[3]);
}

extern "C" void kernel_launch(void* const* d_in, const int* in_sizes, int n_in,
                              void* d_out, int out_size, void* d_ws, size_t ws_size,
                              hipStream_t stream) {
    const float* R     = (const float*)d_in[0];
    const int*   Z     = (const int*)d_in[1];
    const int*   idx   = (const int*)d_in[2];
    const float* a_exp = (const float*)d_in[3];
    const float* a_num = (const float*)d_in[4];
    const float* coef  = (const float*)d_in[5];
    const float* expo  = (const float*)d_in[6];
    float* out = (float*)d_out;

    hipMemsetAsync(out, 0, sizeof(float), stream);  // d_out poisoned each call

    if (ws_size >= (size_t)WS_NEED) {
        float4*        P   = (float4*)d_ws;
        unsigned char* gxy = (unsigned char*)d_ws + XY_OFF;
        unsigned char* gz  = (unsigned char*)d_ws + Z_OFF;
        build_tables<<<(N_ATOMS + 255) / 256, 256, 0, stream>>>(R, Z, P, gxy, gz);
        // 150 KB LDS -> 1 block/CU; 256 blocks x 1024 threads
        zbl_sparse<<<256, 1024, 0, stream>>>(P, gxy, gz, idx,
                                             a_exp, a_num, coef, expo, out);
    } else if (ws_size >= (size_t)TBL_BYTES) {
        float4* P = (float4*)d_ws;
        build_tables<<<(N_ATOMS + 255) / 256, 256, 0, stream>>>(
            R, Z, P, (unsigned char*)d_ws, (unsigned char*)d_ws);  // tails unused
        zbl_mlp<<<2048, 256, 0, stream>>>(P, idx, a_exp, a_num, coef, expo, out);
    }
}

// Round 7
// 116.852 us; speedup vs baseline: 1.5367x; 1.4243x over previous
//
#include <hip/hip_runtime.h>
#include <math.h>

#define N_ATOMS 100000
#define N_EDGES 6400000
#define NZB 50000          // ceil(N_ATOMS/2) z-nibble bytes
#define TBL_BYTES (N_ATOMS * 16)           // float4 P table
#define XY_OFF    TBL_BYTES                // 1,600,000 (16B aligned)
#define Z_OFF     (XY_OFF + N_ATOMS)       // 1,700,000 (16B aligned)
#define WS_NEED   (Z_OFF + NZB)

// cell(x): width-6 cells over [-48,48], clamped. Cell gap >= 2 in any dim
// guarantees |delta| >= 6 -> dr >= 6 -> cos_cutoff == 0 exactly in fp32 ->
// zero contribution. Conservative reject; ~10.5% of edges survive.
__device__ __forceinline__ int cell6(float x) {
    return min(max((int)((x + 48.0f) * (1.0f / 6.0f)), 0), 15);
}

__global__ __launch_bounds__(256)
void build_tables(const float* __restrict__ R, const int* __restrict__ Z,
                  float4* __restrict__ P, unsigned char* __restrict__ gxy,
                  unsigned char* __restrict__ gz) {
    int i = blockIdx.x * blockDim.x + threadIdx.x;
    if (i < N_ATOMS) {
        float x = R[3 * i], y = R[3 * i + 1], z = R[3 * i + 2];
        P[i] = make_float4(x, y, z, (float)Z[i]);
        gxy[i] = (unsigned char)(cell6(x) | (cell6(y) << 4));
    }
    if (i < NZB) {  // one thread per packed z-byte (2 atoms) -> no write race
        int a0 = 2 * i, a1 = 2 * i + 1;
        int c0 = cell6(R[3 * a0 + 2]);
        int c1 = (a1 < N_ATOMS) ? cell6(R[3 * a1 + 2]) : 0;
        gz[i] = (unsigned char)(c0 | (c1 << 4));
    }
}

// R7 = R6 structure + R4's powz LDS LUT restored.
// KEY FINDING (R5/R6 post-mortem): HIP __powf lowers to full-precision
// __ocml_pow_f32 (~100+ branchy instructions), NOT exp2(y*log2(x)).
// Putting it in the hot body quadrupled VALU cycles (R4 30% -> R6 61%
// VALUBusy). Z^a_exp comes from a 64-entry LDS LUT built once per block.
__global__ __launch_bounds__(1024)
void zbl_sparse(const float4* __restrict__ P,
                const unsigned char* __restrict__ gxy,
                const unsigned char* __restrict__ gz,
                const int*    __restrict__ idx,
                const float*  __restrict__ a_exp,
                const float*  __restrict__ a_num,
                const float*  __restrict__ coef,
                const float*  __restrict__ expo,
                float*        __restrict__ out)
{
    __shared__ __align__(16) unsigned char sxy[N_ATOMS];  // 100 KB
    __shared__ __align__(16) unsigned char sz[NZB];       // 50 KB
    __shared__ float powz[64];                            // Z^a_exp LUT
    __shared__ float wave_part[16];

    const int t = threadIdx.x;

    // cooperative LDS table load (uint4-vectorized; sizes divide 16 exactly)
    {
        const uint4* s = (const uint4*)gxy;
        uint4*       d = (uint4*)sxy;
        for (int k = t; k < N_ATOMS / 16; k += 1024) d[k] = s[k];
        const uint4* s2 = (const uint4*)gz;
        uint4*       d2 = (uint4*)sz;
        for (int k = t; k < NZB / 16; k += 1024) d2[k] = s2[k];
    }

    const float aexp     = a_exp[0];
    const float inv_anum = 1.0f / a_num[0];
    const float c0 = coef[0], c1 = coef[1], c2 = coef[2], c3 = coef[3];
    const float e0 = expo[0], e1 = expo[1], e2 = expo[2], e3 = expo[3];
    if (t < 64) powz[t] = __powf((float)t, aexp);  // ocml pow OK here: once
    __syncthreads();

    const int4* idx_i4 = (const int4*)idx;              // idx[0,:]
    const int4* idx_j4 = (const int4*)(idx + N_EDGES);  // idx[1,:]
    const int n4 = N_EDGES / 4;                          // 1.6M exact
    const int tid    = blockIdx.x * blockDim.x + t;
    const int stride = gridDim.x * blockDim.x;

    const float PI_OVER_RMAX = 0.52359877559829887f;  // pi/6

    float acc = 0.0f;
    for (int k = tid; k < n4; k += stride) {
        int4 ii = idx_i4[k];
        int4 jj = idx_j4[k];

        // ---- stage 1a: indices + xy cell test (8 random LDS byte reads) ----
        unsigned ia[4], jb[4];
        bool pxy[4];
#pragma unroll
        for (int u = 0; u < 4; ++u) {
            int i = (&ii.x)[u];
            int j = (&jj.x)[u];
            bool valid = ((unsigned)i < N_ATOMS) & ((unsigned)j < N_ATOMS);
            unsigned a = min((unsigned)i, N_ATOMS - 1u);
            unsigned b = min((unsigned)j, N_ATOMS - 1u);
            ia[u] = a; jb[u] = b;
            int ci = sxy[a], cj = sxy[b];
            int dxy = abs((ci & 15) - (cj & 15)) | abs((ci >> 4) - (cj >> 4));
            pxy[u] = valid & (dxy <= 1);
        }

        // ---- stage 1b: z test, LDS reads predicated on xy pass ----
        bool pass[4];
#pragma unroll
        for (int u = 0; u < 4; ++u) {
            unsigned a = ia[u], b = jb[u];
            unsigned aa = pxy[u] ? (a >> 1) : 0u;
            unsigned ba = pxy[u] ? (b >> 1) : 0u;
            int za = (sz[aa] >> ((a & 1) << 2)) & 15;
            int zb = (sz[ba] >> ((b & 1) << 2)) & 15;
            pass[u] = pxy[u] & (abs(za - zb) <= 1);
        }

        // ---- stage 2a: 8 predicated gathers, all in flight (MLP=8) ----
        // non-pass lanes read P[0]: one broadcast cacheline, TA-coalesced
        float4 pa[4], pb[4];
#pragma unroll
        for (int u = 0; u < 4; ++u) {
            pa[u] = P[pass[u] ? ia[u] : 0u];
            pb[u] = P[pass[u] ? jb[u] : 0u];
        }

        // ---- stage 2b: exec-masked physics; LUT pow, native exp/cos ----
#pragma unroll
        for (int u = 0; u < 4; ++u) {
            float dx = pb[u].x - pa[u].x;
            float dy = pb[u].y - pa[u].y;
            float dz = pb[u].z - pa[u].z;
            float d2 = dx * dx + dy * dy + dz * dz;
            bool live = pass[u] & (d2 < 36.0f);   // pass guards P[0] dummies
            if (live) {
                float dr = fmaxf(sqrtf(d2), 0.02f);  // clip [0.02, 6)
                int zi = (int)pa[u].w, zj = (int)pb[u].w;   // in [1,50)
                float dist = dr * (powz[zi & 63] + powz[zj & 63]) * inv_anum;
                float f = c0 * __expf(-e0 * dist) + c1 * __expf(-e1 * dist)
                        + c2 * __expf(-e2 * dist) + c3 * __expf(-e3 * dist);
                float cc = 0.5f * (__cosf(PI_OVER_RMAX * dr) + 1.0f);
                acc += 0.5f * pa[u].w * pb[u].w / dr * f * cc;
            }
        }
    }

    // wave (64-lane) shuffle reduction, then 16-wave LDS reduction
#pragma unroll
    for (int off = 32; off > 0; off >>= 1)
        acc += __shfl_down(acc, off, 64);
    const int lane = t & 63;
    const int wave = t >> 6;
    if (lane == 0) wave_part[wave] = acc;
    __syncthreads();
    if (t == 0) {
        float s = 0.0f;
#pragma unroll
        for (int w = 0; w < 16; ++w) s += wave_part[w];
        atomicAdd(out, s);
    }
}

// Fallback (ws too small for tables): packed-gather MLP version with LUT.
__global__ __launch_bounds__(256)
void zbl_mlp(const float4* __restrict__ P, const int* __restrict__ idx,
             const float* __restrict__ a_exp, const float* __restrict__ a_num,
             const float* __restrict__ coef, const float* __restrict__ expo,
             float* __restrict__ out)
{
    __shared__ float powz[64];
    __shared__ float wave_part[4];
    const float aexp = a_exp[0];
    const float inv_anum = 1.0f / a_num[0];
    const float c0 = coef[0], c1 = coef[1], c2 = coef[2], c3 = coef[3];
    const float e0 = expo[0], e1 = expo[1], e2 = expo[2], e3 = expo[3];
    const int t = threadIdx.x;
    if (t < 64) powz[t] = __powf((float)t, aexp);
    __syncthreads();
    const int4* idx_i4 = (const int4*)idx;
    const int4* idx_j4 = (const int4*)(idx + N_EDGES);
    const int n4 = N_EDGES / 4;
    const int tid = blockIdx.x * blockDim.x + t;
    const int stride = gridDim.x * blockDim.x;
    const float PI_OVER_RMAX = 0.52359877559829887f;
    float acc = 0.0f;
    for (int k = tid; k < n4; k += stride) {
        int4 ii = idx_i4[k];
        int4 jj = idx_j4[k];
        float4 pa[4], pb[4];
        bool valid[4];
#pragma unroll
        for (int u = 0; u < 4; ++u) {
            int i = (&ii.x)[u], j = (&jj.x)[u];
            valid[u] = ((unsigned)i < N_ATOMS) & ((unsigned)j < N_ATOMS);
            pa[u] = P[min((unsigned)i, N_ATOMS - 1u)];
            pb[u] = P[min((unsigned)j, N_ATOMS - 1u)];
        }
#pragma unroll
        for (int u = 0; u < 4; ++u) {
            float dx = pb[u].x - pa[u].x, dy = pb[u].y - pa[u].y, dz = pb[u].z - pa[u].z;
            float d2 = dx * dx + dy * dy + dz * dz;
            if (valid[u] && d2 < 36.0f) {
                float dr = fmaxf(sqrtf(d2), 0.02f);
                int zi = (int)pa[u].w, zj = (int)pb[u].w;
                float dist = dr * (powz[zi & 63] + powz[zj & 63]) * inv_anum;
                float f = c0 * __expf(-e0 * dist) + c1 * __expf(-e1 * dist)
                        + c2 * __expf(-e2 * dist) + c3 * __expf(-e3 * dist);
                float cc = 0.5f * (__cosf(PI_OVER_RMAX * dr) + 1.0f);
                acc += 0.5f * pa[u].w * pb[u].w / dr * f * cc;
            }
        }
    }
#pragma unroll
    for (int off = 32; off > 0; off >>= 1)
        acc += __shfl_down(acc, off, 64);
    const int lane = t & 63, wave = t >> 6;
    if (lane == 0) wave_part[wave] = acc;
    __syncthreads();
    if (t == 0)
        atomicAdd(out, wave_part[0] + wave_part[1] + wave_part[2] + wave_part[3]);
}

extern "C" void kernel_launch(void* const* d_in, const int* in_sizes, int n_in,
                              void* d_out, int out_size, void* d_ws, size_t ws_size,
                              hipStream_t stream) {
    const float* R     = (const float*)d_in[0];
    const int*   Z     = (const int*)d_in[1];
    const int*   idx   = (const int*)d_in[2];
    const float* a_exp = (const float*)d_in[3];
    const float* a_num = (const float*)d_in[4];
    const float* coef  = (const float*)d_in[5];
    const float* expo  = (const float*)d_in[6];
    float* out = (float*)d_out;

    hipMemsetAsync(out, 0, sizeof(float), stream);  // d_out poisoned each call

    if (ws_size >= (size_t)WS_NEED) {
        float4*        P   = (float4*)d_ws;
        unsigned char* gxy = (unsigned char*)d_ws + XY_OFF;
        unsigned char* gz  = (unsigned char*)d_ws + Z_OFF;
        build_tables<<<(N_ATOMS + 255) / 256, 256, 0, stream>>>(R, Z, P, gxy, gz);
        // 150 KB LDS -> 1 block/CU; 256 blocks x 1024 threads
        zbl_sparse<<<256, 1024, 0, stream>>>(P, gxy, gz, idx,
                                             a_exp, a_num, coef, expo, out);
    } else if (ws_size >= (size_t)TBL_BYTES) {
        float4* P = (float4*)d_ws;
        build_tables<<<(N_ATOMS + 255) / 256, 256, 0, stream>>>(
            R, Z, P, (unsigned char*)d_ws, (unsigned char*)d_ws);  // tails unused
        zbl_mlp<<<2048, 256, 0, stream>>>(P, idx, a_exp, a_num, coef, expo, out);
    }
}

// Round 8
// 113.371 us; speedup vs baseline: 1.5839x; 1.0307x over previous
//
#include <hip/hip_runtime.h>
#include <math.h>

#define N_ATOMS 100000
#define N_EDGES 6400000
#define TBL_BYTES (N_ATOMS * 16)           // float4 P table
#define XY_OFF    TBL_BYTES                // 1,600,000 (16B aligned)
#define WS_NEED   (XY_OFF + N_ATOMS)

// cell(x): width-6 cells over [-48,48], clamped. Cell gap >= 2 in any dim
// guarantees |delta| >= 6 -> dr >= 6 -> cos_cutoff == 0 exactly in fp32 ->
// zero contribution. Conservative reject; xy-only pass rate ~25%.
__device__ __forceinline__ int cell6(float x) {
    return min(max((int)((x + 48.0f) * (1.0f / 6.0f)), 0), 15);
}

__global__ __launch_bounds__(256)
void build_tables(const float* __restrict__ R, const int* __restrict__ Z,
                  float4* __restrict__ P, unsigned char* __restrict__ gxy) {
    int i = blockIdx.x * blockDim.x + threadIdx.x;
    if (i < N_ATOMS) {
        float x = R[3 * i], y = R[3 * i + 1], z = R[3 * i + 2];
        P[i] = make_float4(x, y, z, (float)Z[i]);
        gxy[i] = (unsigned char)(cell6(x) | (cell6(y) << 4));
    }
}

// R8: wave-level survivor compaction. R7 post-mortem: physics bodies ran
// exec-masked with ~1-2 live lanes of 64 (P(any live)=0.71 per u-slot), so
// ~47K cyc/CU of quarter-rate transcendentals did ~2% useful work. Now each
// wave queues pass-edges into a private 128-entry LDS ring and runs the
// physics body only on 64 DENSE lanes. Funding: z-table (50KB) dropped for
// the 16KB queues; pass 10.5%->~25% doubles gather fills (TA pipe, overlapped)
// but cuts body count ~3x and makes every body lane useful.
// HIP __powf = branchy __ocml_pow_f32 (~100 inst) -- LUT only (R5/R6 lesson).
__global__ __launch_bounds__(1024)
void zbl_queue(const float4* __restrict__ P,
               const unsigned char* __restrict__ gxy,
               const int*    __restrict__ idx,
               const float*  __restrict__ a_exp,
               const float*  __restrict__ a_num,
               const float*  __restrict__ coef,
               const float*  __restrict__ expo,
               float*        __restrict__ out)
{
    __shared__ __align__(16) unsigned char sxy[N_ATOMS];  // 100 KB
    __shared__ uint2 q[16 * 128];                         // 16 KB wave rings
    __shared__ float powz[64];                            // Z^a_exp LUT
    __shared__ float wave_part[16];

    const int t = threadIdx.x;

    // cooperative LDS table load (uint4-vectorized; 100000/16 = 6250)
    {
        const uint4* s = (const uint4*)gxy;
        uint4*       d = (uint4*)sxy;
        for (int k = t; k < N_ATOMS / 16; k += 1024) d[k] = s[k];
    }

    const float aexp     = a_exp[0];
    const float inv_anum = 1.0f / a_num[0];
    const float c0 = coef[0], c1 = coef[1], c2 = coef[2], c3 = coef[3];
    const float e0 = expo[0], e1 = expo[1], e2 = expo[2], e3 = expo[3];
    if (t < 64) powz[t] = __powf((float)t, aexp);  // ocml pow OK once at init
    __syncthreads();

    const int lane = t & 63;
    const int wave = t >> 6;
    uint2* myq = &q[wave << 7];          // wave-private ring, no barriers

    const int4* idx_i4 = (const int4*)idx;              // idx[0,:]
    const int4* idx_j4 = (const int4*)(idx + N_EDGES);  // idx[1,:]
    const int n4 = N_EDGES / 4;                          // 1.6M exact
    const int tid    = blockIdx.x * blockDim.x + t;
    const int stride = gridDim.x * blockDim.x;           // 262144
    const int ITERS  = (n4 + stride - 1) / stride;       // 7 (uniform!)

    const float PI_OVER_RMAX = 0.52359877559829887f;  // pi/6
    const unsigned long long lmask = (1ull << lane) - 1ull;

    unsigned qhead = 0, qtail = 0;   // uniform across wave (ballot-derived)
    float acc = 0.0f;

    for (int m = 0; m < ITERS; ++m) {
        int k = tid + m * stride;
        bool kv = k < n4;                      // lane predicate, folded below
        int kc = kv ? k : (n4 - 1);
        int4 ii = idx_i4[kc];
        int4 jj = idx_j4[kc];

#pragma unroll
        for (int u = 0; u < 4; ++u) {
            int i = (&ii.x)[u];
            int j = (&jj.x)[u];
            bool valid = kv & ((unsigned)i < N_ATOMS) & ((unsigned)j < N_ATOMS);
            unsigned a = min((unsigned)i, N_ATOMS - 1u);
            unsigned b = min((unsigned)j, N_ATOMS - 1u);
            int ci = sxy[a], cj = sxy[b];
            int dxy = abs((ci & 15) - (cj & 15)) | abs((ci >> 4) - (cj >> 4));
            bool pass = valid & (dxy <= 1);

            // ---- wave compaction: push survivors into the ring ----
            unsigned long long mk = __ballot(pass);
            unsigned cnt   = (unsigned)__popcll(mk);
            unsigned myoff = (unsigned)__popcll(mk & lmask);
            if (pass) myq[(qtail + myoff) & 127] = make_uint2(a, b);
            qtail += cnt;                       // uniform

            // ---- dense physics body: 64 useful lanes per execution ----
            if (qtail - qhead >= 64) {          // uniform branch
                uint2 e = myq[(qhead + lane) & 127];
                qhead += 64;
                float4 pi = P[e.x];
                float4 pj = P[e.y];
                float dx = pj.x - pi.x, dy = pj.y - pi.y, dz = pj.z - pi.z;
                float d2 = dx * dx + dy * dy + dz * dz;
                if (d2 < 36.0f) {               // ~8% of dense lanes
                    float dr = fmaxf(sqrtf(d2), 0.02f);
                    int zi = (int)pi.w, zj = (int)pj.w;
                    float dist = dr * (powz[zi & 63] + powz[zj & 63]) * inv_anum;
                    float f = c0 * __expf(-e0 * dist) + c1 * __expf(-e1 * dist)
                            + c2 * __expf(-e2 * dist) + c3 * __expf(-e3 * dist);
                    float cc = 0.5f * (__cosf(PI_OVER_RMAX * dr) + 1.0f);
                    acc += 0.5f * pi.w * pj.w / dr * f * cc;
                }
            }
        }
    }

    // ---- flush remaining (<64) queued edges ----
    while (qtail != qhead) {                    // uniform condition
        unsigned n = min(64u, qtail - qhead);
        if (lane < n) {
            uint2 e = myq[(qhead + lane) & 127];
            float4 pi = P[e.x];
            float4 pj = P[e.y];
            float dx = pj.x - pi.x, dy = pj.y - pi.y, dz = pj.z - pi.z;
            float d2 = dx * dx + dy * dy + dz * dz;
            if (d2 < 36.0f) {
                float dr = fmaxf(sqrtf(d2), 0.02f);
                int zi = (int)pi.w, zj = (int)pj.w;
                float dist = dr * (powz[zi & 63] + powz[zj & 63]) * inv_anum;
                float f = c0 * __expf(-e0 * dist) + c1 * __expf(-e1 * dist)
                        + c2 * __expf(-e2 * dist) + c3 * __expf(-e3 * dist);
                float cc = 0.5f * (__cosf(PI_OVER_RMAX * dr) + 1.0f);
                acc += 0.5f * pi.w * pj.w / dr * f * cc;
            }
        }
        qhead += n;
    }

    // wave (64-lane) shuffle reduction, then 16-wave LDS reduction
#pragma unroll
    for (int off = 32; off > 0; off >>= 1)
        acc += __shfl_down(acc, off, 64);
    if (lane == 0) wave_part[wave] = acc;
    __syncthreads();
    if (t == 0) {
        float s = 0.0f;
#pragma unroll
        for (int w = 0; w < 16; ++w) s += wave_part[w];
        atomicAdd(out, s);
    }
}

// Fallback (ws too small for tables): packed-gather MLP version with LUT.
__global__ __launch_bounds__(256)
void zbl_mlp(const float4* __restrict__ P, const int* __restrict__ idx,
             const float* __restrict__ a_exp, const float* __restrict__ a_num,
             const float* __restrict__ coef, const float* __restrict__ expo,
             float* __restrict__ out)
{
    __shared__ float powz[64];
    __shared__ float wave_part[4];
    const float aexp = a_exp[0];
    const float inv_anum = 1.0f / a_num[0];
    const float c0 = coef[0], c1 = coef[1], c2 = coef[2], c3 = coef[3];
    const float e0 = expo[0], e1 = expo[1], e2 = expo[2], e3 = expo[3];
    const int t = threadIdx.x;
    if (t < 64) powz[t] = __powf((float)t, aexp);
    __syncthreads();
    const int4* idx_i4 = (const int4*)idx;
    const int4* idx_j4 = (const int4*)(idx + N_EDGES);
    const int n4 = N_EDGES / 4;
    const int tid = blockIdx.x * blockDim.x + t;
    const int stride = gridDim.x * blockDim.x;
    const float PI_OVER_RMAX = 0.52359877559829887f;
    float acc = 0.0f;
    for (int k = tid; k < n4; k += stride) {
        int4 ii = idx_i4[k];
        int4 jj = idx_j4[k];
        float4 pa[4], pb[4];
        bool valid[4];
#pragma unroll
        for (int u = 0; u < 4; ++u) {
            int i = (&ii.x)[u], j = (&jj.x)[u];
            valid[u] = ((unsigned)i < N_ATOMS) & ((unsigned)j < N_ATOMS);
            pa[u] = P[min((unsigned)i, N_ATOMS - 1u)];
            pb[u] = P[min((unsigned)j, N_ATOMS - 1u)];
        }
#pragma unroll
        for (int u = 0; u < 4; ++u) {
            float dx = pb[u].x - pa[u].x, dy = pb[u].y - pa[u].y, dz = pb[u].z - pa[u].z;
            float d2 = dx * dx + dy * dy + dz * dz;
            if (valid[u] && d2 < 36.0f) {
                float dr = fmaxf(sqrtf(d2), 0.02f);
                int zi = (int)pa[u].w, zj = (int)pb[u].w;
                float dist = dr * (powz[zi & 63] + powz[zj & 63]) * inv_anum;
                float f = c0 * __expf(-e0 * dist) + c1 * __expf(-e1 * dist)
                        + c2 * __expf(-e2 * dist) + c3 * __expf(-e3 * dist);
                float cc = 0.5f * (__cosf(PI_OVER_RMAX * dr) + 1.0f);
                acc += 0.5f * pa[u].w * pb[u].w / dr * f * cc;
            }
        }
    }
#pragma unroll
    for (int off = 32; off > 0; off >>= 1)
        acc += __shfl_down(acc, off, 64);
    const int lane = t & 63, wave = t >> 6;
    if (lane == 0) wave_part[wave] = acc;
    __syncthreads();
    if (t == 0)
        atomicAdd(out, wave_part[0] + wave_part[1] + wave_part[2] + wave_part[3]);
}

extern "C" void kernel_launch(void* const* d_in, const int* in_sizes, int n_in,
                              void* d_out, int out_size, void* d_ws, size_t ws_size,
                              hipStream_t stream) {
    const float* R     = (const float*)d_in[0];
    const int*   Z     = (const int*)d_in[1];
    const int*   idx   = (const int*)d_in[2];
    const float* a_exp = (const float*)d_in[3];
    const float* a_num = (const float*)d_in[4];
    const float* coef  = (const float*)d_in[5];
    const float* expo  = (const float*)d_in[6];
    float* out = (float*)d_out;

    hipMemsetAsync(out, 0, sizeof(float), stream);  // d_out poisoned each call

    if (ws_size >= (size_t)WS_NEED) {
        float4*        P   = (float4*)d_ws;
        unsigned char* gxy = (unsigned char*)d_ws + XY_OFF;
        build_tables<<<(N_ATOMS + 255) / 256, 256, 0, stream>>>(R, Z, P, gxy);
        // ~117 KB LDS -> 1 block/CU; 256 blocks x 1024 threads
        zbl_queue<<<256, 1024, 0, stream>>>(P, gxy, idx,
                                            a_exp, a_num, coef, expo, out);
    } else if (ws_size >= (size_t)TBL_BYTES) {
        float4* P = (float4*)d_ws;
        build_tables<<<(N_ATOMS + 255) / 256, 256, 0, stream>>>(
            R, Z, P, (unsigned char*)d_ws);  // gxy tail unused by zbl_mlp
        zbl_mlp<<<2048, 256, 0, stream>>>(P, idx, a_exp, a_num, coef, expo, out);
    }
}

// Round 9
// 112.392 us; speedup vs baseline: 1.5977x; 1.0087x over previous
//
#include <hip/hip_runtime.h>
#include <math.h>

#define N_ATOMS 100000
#define N_EDGES 6400000
#define NZB 50000          // ceil(N_ATOMS/2) z-nibble bytes
#define TBL_BYTES (N_ATOMS * 16)           // float4 P table
#define XY_OFF    TBL_BYTES                // 1,600,000 (16B aligned)
#define Z_OFF     (XY_OFF + N_ATOMS)       // 1,700,000
#define WS_NEED   (Z_OFF + NZB)

// cell(x): width-6 cells over [-48,48], clamped. Cell gap >= 2 in any dim
// guarantees |delta| >= 6 -> dr >= 6 -> cos_cutoff == 0 exactly in fp32 ->
// zero contribution (validated absmax=0.0 across R4-R8). 3D pass ~10.5%.
__device__ __forceinline__ int cell6(float x) {
    return min(max((int)((x + 48.0f) * (1.0f / 6.0f)), 0), 15);
}

__global__ __launch_bounds__(256)
void build_tables(const float* __restrict__ R, const int* __restrict__ Z,
                  float4* __restrict__ P, unsigned char* __restrict__ gxy,
                  unsigned char* __restrict__ gz) {
    int i = blockIdx.x * blockDim.x + threadIdx.x;
    if (i < N_ATOMS) {
        float x = R[3 * i], y = R[3 * i + 1], z = R[3 * i + 2];
        P[i] = make_float4(x, y, z, (float)Z[i]);
        gxy[i] = (unsigned char)(cell6(x) | (cell6(y) << 4));
    }
    if (i < NZB) {  // one thread per packed z-byte (2 atoms) -> no write race
        int a0 = 2 * i, a1 = 2 * i + 1;
        int c0 = cell6(R[3 * a0 + 2]);
        int c1 = (a1 < N_ATOMS) ? cell6(R[3 * a1 + 2]) : 0;
        gz[i] = (unsigned char)(c0 | (c1 << 4));
    }
}

// Shared physics body: dense drain of n queued edges (exec-masked lane<n).
__device__ __forceinline__ float zbl_body(const float4* __restrict__ P,
                                          const float* powz, uint2 e,
                                          float inv_anum,
                                          float c0, float c1, float c2, float c3,
                                          float e0, float e1, float e2, float e3) {
    const float PI_OVER_RMAX = 0.52359877559829887f;  // pi/6
    float4 pi = P[e.x];
    float4 pj = P[e.y];
    float dx = pj.x - pi.x, dy = pj.y - pi.y, dz = pj.z - pi.z;
    float d2 = dx * dx + dy * dy + dz * dz;
    if (d2 >= 36.0f) return 0.0f;          // cell test is conservative
    float dr = fmaxf(sqrtf(d2), 0.02f);    // clip [0.02, 6)
    int zi = (int)pi.w, zj = (int)pj.w;    // in [1,50)
    float dist = dr * (powz[zi & 63] + powz[zj & 63]) * inv_anum;
    float f = c0 * __expf(-e0 * dist) + c1 * __expf(-e1 * dist)
            + c2 * __expf(-e2 * dist) + c3 * __expf(-e3 * dist);
    float cc = 0.5f * (__cosf(PI_OVER_RMAX * dr) + 1.0f);
    return 0.5f * pi.w * pj.w / dr * f * cc;
}

// R9 = R8 queue + R7 z-table (both, not either/or).
// R8 post-mortem: dropping the z-test (to fund a 128-entry ring) raised pass
// 10.5%->25%; dense-body gather line-fills (~128/body, ~3.1cyc each) became
// ~39K cyc/CU -- the queue's trans saving was spent on fills. Fix: 64-entry
// ring with drain-BEFORE-push on overflow (drains ~60 lanes avg), freeing
// 8KB so sxy(100K)+sz(50K)+q(8K)+LUT = ~158.6KB fits the 160KB WG limit.
// HIP __powf = branchy __ocml_pow_f32 -> LDS LUT only (R5/R6 lesson).
__global__ __launch_bounds__(1024)
void zbl_qz(const float4* __restrict__ P,
            const unsigned char* __restrict__ gxy,
            const unsigned char* __restrict__ gz,
            const int*    __restrict__ idx,
            const float*  __restrict__ a_exp,
            const float*  __restrict__ a_num,
            const float*  __restrict__ coef,
            const float*  __restrict__ expo,
            float*        __restrict__ out)
{
    __shared__ __align__(16) unsigned char sxy[N_ATOMS];  // 100 KB
    __shared__ __align__(16) unsigned char sz[NZB];       // 50 KB
    __shared__ uint2 q[16 * 64];                          // 8 KB wave rings
    __shared__ float powz[64];                            // Z^a_exp LUT
    __shared__ float wave_part[16];

    const int t = threadIdx.x;

    // cooperative LDS table loads (uint4-vectorized; both sizes /16 exact)
    {
        const uint4* s = (const uint4*)gxy;
        uint4*       d = (uint4*)sxy;
        for (int k = t; k < N_ATOMS / 16; k += 1024) d[k] = s[k];
        const uint4* s2 = (const uint4*)gz;
        uint4*       d2 = (uint4*)sz;
        for (int k = t; k < NZB / 16; k += 1024) d2[k] = s2[k];
    }

    const float aexp     = a_exp[0];
    const float inv_anum = 1.0f / a_num[0];
    const float c0 = coef[0], c1 = coef[1], c2 = coef[2], c3 = coef[3];
    const float e0 = expo[0], e1 = expo[1], e2 = expo[2], e3 = expo[3];
    if (t < 64) powz[t] = __powf((float)t, aexp);  // ocml pow OK once at init
    __syncthreads();

    const int lane = t & 63;
    const int wave = t >> 6;
    uint2* myq = &q[wave << 6];          // wave-private 64-entry ring

    const int4* idx_i4 = (const int4*)idx;              // idx[0,:]
    const int4* idx_j4 = (const int4*)(idx + N_EDGES);  // idx[1,:]
    const int n4 = N_EDGES / 4;                          // 1.6M exact
    const int tid    = blockIdx.x * blockDim.x + t;
    const int stride = gridDim.x * blockDim.x;           // 262144
    const int ITERS  = (n4 + stride - 1) / stride;       // 7, uniform

    const unsigned long long lmask = (1ull << lane) - 1ull;

    unsigned qhead = 0, qtail = 0;   // wave-uniform (ballot-derived)
    float acc = 0.0f;

    for (int m = 0; m < ITERS; ++m) {
        int k = tid + m * stride;
        bool kv = k < n4;
        int kc = kv ? k : (n4 - 1);
        int4 ii = idx_i4[kc];
        int4 jj = idx_j4[kc];

#pragma unroll
        for (int u = 0; u < 4; ++u) {
            int i = (&ii.x)[u];
            int j = (&jj.x)[u];
            bool valid = kv & ((unsigned)i < N_ATOMS) & ((unsigned)j < N_ATOMS);
            unsigned a = min((unsigned)i, N_ATOMS - 1u);
            unsigned b = min((unsigned)j, N_ATOMS - 1u);
            int ci = sxy[a], cj = sxy[b];
            int dxy = abs((ci & 15) - (cj & 15)) | abs((ci >> 4) - (cj >> 4));
            bool pxy = valid & (dxy <= 1);
            // z test: reads predicated on xy pass (masked lanes -> sz[0]
            // broadcast, conflict-free)
            unsigned aa = pxy ? (a >> 1) : 0u;
            unsigned ba = pxy ? (b >> 1) : 0u;
            int za = (sz[aa] >> ((a & 1) << 2)) & 15;
            int zb = (sz[ba] >> ((b & 1) << 2)) & 15;
            bool pass = pxy & (abs(za - zb) <= 1);

            unsigned long long mk = __ballot(pass);
            unsigned cnt   = (unsigned)__popcll(mk);
            unsigned myoff = (unsigned)__popcll(mk & lmask);

            // drain BEFORE push if the 64-entry ring would overflow
            unsigned pending = qtail - qhead;
            if (pending + cnt > 64u) {          // uniform branch
                if (lane < (int)pending) {
                    uint2 e = myq[(qhead + lane) & 63];
                    acc += zbl_body(P, powz, e, inv_anum,
                                    c0, c1, c2, c3, e0, e1, e2, e3);
                }
                qhead = qtail;                  // pending -> 0
            }
            if (pass) myq[(qtail + myoff) & 63] = make_uint2(a, b);
            qtail += cnt;
        }
    }

    // flush (pending <= 64 by construction)
    {
        unsigned pending = qtail - qhead;
        if (lane < (int)pending) {
            uint2 e = myq[(qhead + lane) & 63];
            acc += zbl_body(P, powz, e, inv_anum,
                            c0, c1, c2, c3, e0, e1, e2, e3);
        }
    }

    // wave (64-lane) shuffle reduction, then 16-wave LDS reduction
#pragma unroll
    for (int off = 32; off > 0; off >>= 1)
        acc += __shfl_down(acc, off, 64);
    if (lane == 0) wave_part[wave] = acc;
    __syncthreads();
    if (t == 0) {
        float s = 0.0f;
#pragma unroll
        for (int w = 0; w < 16; ++w) s += wave_part[w];
        atomicAdd(out, s);
    }
}

// Fallback (ws too small for tables): packed-gather MLP version with LUT.
__global__ __launch_bounds__(256)
void zbl_mlp(const float4* __restrict__ P, const int* __restrict__ idx,
             const float* __restrict__ a_exp, const float* __restrict__ a_num,
             const float* __restrict__ coef, const float* __restrict__ expo,
             float* __restrict__ out)
{
    __shared__ float powz[64];
    __shared__ float wave_part[4];
    const float aexp = a_exp[0];
    const float inv_anum = 1.0f / a_num[0];
    const float c0 = coef[0], c1 = coef[1], c2 = coef[2], c3 = coef[3];
    const float e0 = expo[0], e1 = expo[1], e2 = expo[2], e3 = expo[3];
    const int t = threadIdx.x;
    if (t < 64) powz[t] = __powf((float)t, aexp);
    __syncthreads();
    const int4* idx_i4 = (const int4*)idx;
    const int4* idx_j4 = (const int4*)(idx + N_EDGES);
    const int n4 = N_EDGES / 4;
    const int tid = blockIdx.x * blockDim.x + t;
    const int stride = gridDim.x * blockDim.x;
    const float PI_OVER_RMAX = 0.52359877559829887f;
    float acc = 0.0f;
    for (int k = tid; k < n4; k += stride) {
        int4 ii = idx_i4[k];
        int4 jj = idx_j4[k];
        float4 pa[4], pb[4];
        bool valid[4];
#pragma unroll
        for (int u = 0; u < 4; ++u) {
            int i = (&ii.x)[u], j = (&jj.x)[u];
            valid[u] = ((unsigned)i < N_ATOMS) & ((unsigned)j < N_ATOMS);
            pa[u] = P[min((unsigned)i, N_ATOMS - 1u)];
            pb[u] = P[min((unsigned)j, N_ATOMS - 1u)];
        }
#pragma unroll
        for (int u = 0; u < 4; ++u) {
            float dx = pb[u].x - pa[u].x, dy = pb[u].y - pa[u].y, dz = pb[u].z - pa[u].z;
            float d2 = dx * dx + dy * dy + dz * dz;
            if (valid[u] && d2 < 36.0f) {
                float dr = fmaxf(sqrtf(d2), 0.02f);
                int zi = (int)pa[u].w, zj = (int)pb[u].w;
                float dist = dr * (powz[zi & 63] + powz[zj & 63]) * inv_anum;
                float f = c0 * __expf(-e0 * dist) + c1 * __expf(-e1 * dist)
                        + c2 * __expf(-e2 * dist) + c3 * __expf(-e3 * dist);
                float cc = 0.5f * (__cosf(PI_OVER_RMAX * dr) + 1.0f);
                acc += 0.5f * pa[u].w * pb[u].w / dr * f * cc;
            }
        }
    }
#pragma unroll
    for (int off = 32; off > 0; off >>= 1)
        acc += __shfl_down(acc, off, 64);
    const int lane = t & 63, wave = t >> 6;
    if (lane == 0) wave_part[wave] = acc;
    __syncthreads();
    if (t == 0)
        atomicAdd(out, wave_part[0] + wave_part[1] + wave_part[2] + wave_part[3]);
}

extern "C" void kernel_launch(void* const* d_in, const int* in_sizes, int n_in,
                              void* d_out, int out_size, void* d_ws, size_t ws_size,
                              hipStream_t stream) {
    const float* R     = (const float*)d_in[0];
    const int*   Z     = (const int*)d_in[1];
    const int*   idx   = (const int*)d_in[2];
    const float* a_exp = (const float*)d_in[3];
    const float* a_num = (const float*)d_in[4];
    const float* coef  = (const float*)d_in[5];
    const float* expo  = (const float*)d_in[6];
    float* out = (float*)d_out;

    hipMemsetAsync(out, 0, sizeof(float), stream);  // d_out poisoned each call

    if (ws_size >= (size_t)WS_NEED) {
        float4*        P   = (float4*)d_ws;
        unsigned char* gxy = (unsigned char*)d_ws + XY_OFF;
        unsigned char* gz  = (unsigned char*)d_ws + Z_OFF;
        build_tables<<<(N_ATOMS + 255) / 256, 256, 0, stream>>>(R, Z, P, gxy, gz);
        // ~158.6 KB LDS -> 1 block/CU; 256 blocks x 1024 threads
        zbl_qz<<<256, 1024, 0, stream>>>(P, gxy, gz, idx,
                                         a_exp, a_num, coef, expo, out);
    } else if (ws_size >= (size_t)TBL_BYTES) {
        float4* P = (float4*)d_ws;
        build_tables<<<(N_ATOMS + 255) / 256, 256, 0, stream>>>(
            R, Z, P, (unsigned char*)d_ws, (unsigned char*)d_ws);  // tails unused
        zbl_mlp<<<2048, 256, 0, stream>>>(P, idx, a_exp, a_num, coef, expo, out);
    }
}